// Round 3
// baseline (874.096 us; speedup 1.0000x reference)
//
#include <hip/hip_runtime.h>
#include <hip/hip_bf16.h>

#define CC 16
#define BB 16384
#define DD 256
#define BT 16
#define NT 256
#define SLAB ((size_t)BB * DD)

typedef float f32x4 __attribute__((ext_vector_type(4)));
typedef short bf16x8 __attribute__((ext_vector_type(8)));

static __device__ __forceinline__ short bfc(float f) {
    return (short)__builtin_bit_cast(unsigned short, __float2bfloat16(f));
}
static __device__ __forceinline__ bf16x8 pack8(f32x4 a, f32x4 b) {
    bf16x8 v;
    v[0] = bfc(a[0]); v[1] = bfc(a[1]); v[2] = bfc(a[2]); v[3] = bfc(a[3]);
    v[4] = bfc(b[0]); v[5] = bfc(b[1]); v[6] = bfc(b[2]); v[7] = bfc(b[3]);
    return v;
}
static __device__ __forceinline__ float sigm(float x) {
    return __builtin_amdgcn_rcpf(1.0f + __expf(-x));
}
static __device__ __forceinline__ float tanh_(float x) {
    return 2.0f * __builtin_amdgcn_rcpf(1.0f + __expf(-2.0f * x)) - 1.0f;
}

// TreeLSTM node update. 256 thr = 4 waves; BT=16 rows x 256 cols per block.
// Wave owns 64 output cols (4 n-frags) -> 8 ds_read_b128 : 32 MFMA per child.
// bf16 LDS h-tile [16][256], XOR-swizzled (chunk ^= row&7), double-buffered,
// ONE raw s_barrier per child (lgkmcnt(0) before it; global loads cross it).
__global__ __launch_bounds__(NT, 3) void treelstm(
    const float* __restrict__ cmem,   // [C][B][D]
    const float* __restrict__ chid,   // [C][B][D]
    const float* __restrict__ Wf,     // [D][D]
    const float* __restrict__ bfv,    // [D]
    const float* __restrict__ Wiou,   // [3D][D]
    const float* __restrict__ biou,   // [3D]
    float* __restrict__ out)          // [2][B][D]
{
    __shared__ __align__(64) unsigned char hb[2][BT * DD * 2];   // 2 x 8 KiB

    const int tid  = threadIdx.x;
    const int lane = tid & 63;
    const int wid  = tid >> 6;     // 0..3
    const int l15  = lane & 15;
    const int l4   = lane >> 4;    // 0..3
    const int b0   = blockIdx.x * BT;
    const int wc0  = wid * 64;     // wave's 64 output columns

    // staging: thread owns (row srow, cols scol..scol+15)
    const int srow = tid & 15;
    const int scol = (tid >> 4) * 16;
    const float* hg = chid + (size_t)(b0 + srow) * DD + scol;
    const int wb0 = srow * 512 + ((scol * 2) ^ ((srow & 7) << 4));
    const int wb1 = wb0 ^ 16;

    // issue h(0) loads before the Wf-fragment setup (setup hides latency)
    f32x4 vA0 = *(const f32x4*)(hg);
    f32x4 vA1 = *(const f32x4*)(hg + 4);
    f32x4 vA2 = *(const f32x4*)(hg + 8);
    f32x4 vA3 = *(const f32x4*)(hg + 12);

    // Wf B-frags in registers for the whole c-loop: 4 n-frags x 8 k = 64 VGPR
    bf16x8 wfr[4][8];
    float bfr[4];
#pragma unroll
    for (int n = 0; n < 4; ++n) {
        const float* wrow = Wf + (size_t)(wc0 + n * 16 + l15) * DD + l4 * 8;
#pragma unroll
        for (int k = 0; k < 8; ++k) {
            f32x4 x0 = *(const f32x4*)(wrow + k * 32);
            f32x4 x1 = *(const f32x4*)(wrow + k * 32 + 4);
            wfr[n][k] = pack8(x0, x1);
        }
        bfr[n] = bfv[wc0 + n * 16 + l15];
    }

    float hs[16];
#pragma unroll
    for (int i = 0; i < 16; ++i) hs[i] = 0.f;
    float nmv[4][4];
#pragma unroll
    for (int n = 0; n < 4; ++n)
#pragma unroll
        for (int j = 0; j < 4; ++j) nmv[n][j] = 0.f;

    const float* cmp = cmem + (size_t)(b0 + l4 * 4) * DD + wc0 + l15;
    const int sw15 = (l15 & 7) << 4;

#pragma unroll
    for (int c = 0; c < CC; ++c) {
        // ---- issue h(c+1): a full iteration of latency hiding
        f32x4 vB0, vB1, vB2, vB3;
        if (c + 1 < CC) {
            const float* hgn = hg + (size_t)(c + 1) * SLAB;
            vB0 = *(const f32x4*)(hgn);
            vB1 = *(const f32x4*)(hgn + 4);
            vB2 = *(const f32x4*)(hgn + 8);
            vB3 = *(const f32x4*)(hgn + 12);
        }
        // ---- issue cm(c): hidden under pack+barrier+MFMA phase
        const float* cmc = cmp + (size_t)c * SLAB;
        float cmv[4][4];
#pragma unroll
        for (int n = 0; n < 4; ++n)
#pragma unroll
            for (int j = 0; j < 4; ++j)
                cmv[n][j] = cmc[j * DD + n * 16];

        // ---- hs += h(c); pack h(c) -> LDS buf[c&1]
#pragma unroll
        for (int i = 0; i < 4; ++i) {
            hs[i]      += vA0[i];
            hs[4 + i]  += vA1[i];
            hs[8 + i]  += vA2[i];
            hs[12 + i] += vA3[i];
        }
        *(bf16x8*)(&hb[c & 1][0] + wb0) = pack8(vA0, vA1);
        *(bf16x8*)(&hb[c & 1][0] + wb1) = pack8(vA2, vA3);

        // ---- write -> read visibility: lgkm drain + raw barrier.
        // Global loads (vB*, cmv) stay in flight across it (no vmcnt drain).
        asm volatile("s_waitcnt lgkmcnt(0)" ::: "memory");
        __builtin_amdgcn_s_barrier();
        __builtin_amdgcn_sched_barrier(0);

        // ---- forget-gate GEMM: 8 ds_read_b128 feed 32 MFMA
        f32x4 acc[4];
#pragma unroll
        for (int n = 0; n < 4; ++n)
            acc[n] = (f32x4){bfr[n], bfr[n], bfr[n], bfr[n]};
        const unsigned char* bc = &hb[c & 1][0] + l15 * 512;
#pragma unroll
        for (int kk = 0; kk < 8; ++kk) {
            bf16x8 a = *(const bf16x8*)(bc + (((kk << 6) + (l4 << 4)) ^ sw15));
            acc[0] = __builtin_amdgcn_mfma_f32_16x16x32_bf16(a, wfr[0][kk], acc[0], 0, 0, 0);
            acc[1] = __builtin_amdgcn_mfma_f32_16x16x32_bf16(a, wfr[1][kk], acc[1], 0, 0, 0);
            acc[2] = __builtin_amdgcn_mfma_f32_16x16x32_bf16(a, wfr[2][kk], acc[2], 0, 0, 0);
            acc[3] = __builtin_amdgcn_mfma_f32_16x16x32_bf16(a, wfr[3][kk], acc[3], 0, 0, 0);
        }

        // ---- node_memory += sigmoid(fg) * cm
#pragma unroll
        for (int n = 0; n < 4; ++n)
#pragma unroll
            for (int j = 0; j < 4; ++j)
                nmv[n][j] += sigm(acc[n][j]) * cmv[n][j];

        if (c + 1 < CC) { vA0 = vB0; vA1 = vB1; vA2 = vB2; vA3 = vB3; }
    }

    // ---- epilogue: hidden_sum -> LDS buf0 (staging slots), then iou GEMM
    {
        f32x4 h0 = {hs[0], hs[1], hs[2], hs[3]};
        f32x4 h1 = {hs[4], hs[5], hs[6], hs[7]};
        f32x4 h2 = {hs[8], hs[9], hs[10], hs[11]};
        f32x4 h3 = {hs[12], hs[13], hs[14], hs[15]};
        *(bf16x8*)(&hb[0][0] + wb0) = pack8(h0, h1);
        *(bf16x8*)(&hb[0][0] + wb1) = pack8(h2, h3);
    }
    asm volatile("s_waitcnt lgkmcnt(0)" ::: "memory");
    __builtin_amdgcn_s_barrier();
    __builtin_amdgcn_sched_barrier(0);

    bf16x8 afr[8];
    {
        const unsigned char* bc0 = &hb[0][0] + l15 * 512;
#pragma unroll
        for (int kk = 0; kk < 8; ++kk)
            afr[kk] = *(const bf16x8*)(bc0 + (((kk << 6) + (l4 << 4)) ^ sw15));
    }

    float gq[3][4][4];
#pragma unroll
    for (int q = 0; q < 3; ++q) {
#pragma unroll
        for (int n = 0; n < 4; ++n) {
            const float* wrow = Wiou + (size_t)(q * DD + wc0 + n * 16 + l15) * DD + l4 * 8;
            f32x4 acc = (f32x4){0.f, 0.f, 0.f, 0.f};
#pragma unroll
            for (int kk = 0; kk < 8; ++kk) {
                f32x4 x0 = *(const f32x4*)(wrow + kk * 32);
                f32x4 x1 = *(const f32x4*)(wrow + kk * 32 + 4);
                acc = __builtin_amdgcn_mfma_f32_16x16x32_bf16(afr[kk], pack8(x0, x1), acc, 0, 0, 0);
            }
            float bq = biou[q * DD + wc0 + n * 16 + l15];
#pragma unroll
            for (int j = 0; j < 4; ++j) gq[q][n][j] = acc[j] + bq;
        }
    }

    // ---- gates + stores
    float* o0 = out + (size_t)(b0 + l4 * 4) * DD + wc0 + l15;
    float* o1 = o0 + SLAB;
#pragma unroll
    for (int n = 0; n < 4; ++n)
#pragma unroll
        for (int j = 0; j < 4; ++j) {
            float ig = sigm(gq[0][n][j]);
            float og = sigm(gq[1][n][j]);
            float ug = tanh_(gq[2][n][j]);
            float mm = nmv[n][j] + ig * ug;
            float hh = og * tanh_(mm);
            o0[j * DD + n * 16] = mm;
            o1[j * DD + n * 16] = hh;
        }
}

extern "C" void kernel_launch(void* const* d_in, const int* in_sizes, int n_in,
                              void* d_out, int out_size, void* d_ws, size_t ws_size,
                              hipStream_t stream) {
    const float* cmem = (const float*)d_in[0];
    const float* chid = (const float*)d_in[1];
    const float* Wf   = (const float*)d_in[2];
    const float* bf   = (const float*)d_in[3];
    const float* Wiou = (const float*)d_in[4];
    const float* biou = (const float*)d_in[5];
    float* out = (float*)d_out;

    treelstm<<<BB / BT, NT, 0, stream>>>(cmem, chid, Wf, bf, Wiou, biou, out);
}

// Round 4
// 162.842 us; speedup vs baseline: 5.3678x; 5.3678x over previous
//
#include <hip/hip_runtime.h>
#include <hip/hip_bf16.h>

#define CC 16
#define BB 16384
#define DD 256
#define BT 16
#define NT 512
#define SLAB ((size_t)BB * DD)

typedef float f32x4 __attribute__((ext_vector_type(4)));
typedef short bf16x8 __attribute__((ext_vector_type(8)));
typedef short bf16x4 __attribute__((ext_vector_type(4)));

static __device__ __forceinline__ short bfc(float f) {
    return (short)__builtin_bit_cast(unsigned short, __float2bfloat16(f));
}
static __device__ __forceinline__ bf16x8 pack8(f32x4 a, f32x4 b) {
    bf16x8 v;
    v[0] = bfc(a[0]); v[1] = bfc(a[1]); v[2] = bfc(a[2]); v[3] = bfc(a[3]);
    v[4] = bfc(b[0]); v[5] = bfc(b[1]); v[6] = bfc(b[2]); v[7] = bfc(b[3]);
    return v;
}
static __device__ __forceinline__ float sigm(float x) {
    return __builtin_amdgcn_rcpf(1.0f + __expf(-x));
}
static __device__ __forceinline__ float tanh_(float x) {
    return 2.0f * __builtin_amdgcn_rcpf(1.0f + __expf(-2.0f * x)) - 1.0f;
}

// ---- prep: pack Wf (rows 0..255) + Wiou (rows 256..1023) f32 -> bf16 row-major
__global__ void prep(const float* __restrict__ Wf, const float* __restrict__ Wiou,
                     short* __restrict__ ws) {
    const int row = blockIdx.x;          // 0..1023
    const int t   = threadIdx.x;         // 0..63
    const float* src = (row < 256) ? (Wf + (size_t)row * DD)
                                   : (Wiou + (size_t)(row - 256) * DD);
    f32x4 v = *(const f32x4*)(src + t * 4);
    bf16x4 o; o[0] = bfc(v[0]); o[1] = bfc(v[1]); o[2] = bfc(v[2]); o[3] = bfc(v[3]);
    *(bf16x4*)(ws + (size_t)row * DD + t * 4) = o;
}

// ---- main: TreeLSTM node update.
// 512 thr = 8 waves; BT=16 rows x 256 cols per block; wave owns 32 cols.
// bf16 LDS h-tile [16][256] XOR-swizzled, double-buffered; one raw s_barrier
// per child (lgkmcnt-only drain, global loads cross it). h prefetched 2 ahead,
// cm 1 ahead. Unroll-by-2 for buffer parity only.
__global__ __launch_bounds__(NT, 3) void treelstm(
    const float* __restrict__ cmem,   // [C][B][D]
    const float* __restrict__ chid,   // [C][B][D]
    const short* __restrict__ wpk,    // packed bf16: Wf rows 0..255, Wiou 256..1023
    const float* __restrict__ bfv,    // [D]
    const float* __restrict__ biou,   // [3D]
    float* __restrict__ out)          // [2][B][D]
{
    __shared__ __align__(64) unsigned char hb[2][BT * DD * 2];   // 2 x 8 KiB

    const int tid  = threadIdx.x;
    const int lane = tid & 63;
    const int wid  = tid >> 6;     // 0..7
    const int l15  = lane & 15;
    const int l4   = lane >> 4;    // 0..3
    const int b0   = blockIdx.x * BT;
    const int wc0  = wid * 32;     // wave's 32 output columns
    const int sw15 = (l15 & 7) << 4;

    // staging: thread owns (row tid>>5, cols (tid&31)*8 .. +7)
    const int srow = tid >> 5;
    const int scol = (tid & 31) * 8;
    const float* hg = chid + (size_t)(b0 + srow) * DD + scol;
    const int wb = srow * 512 + ((scol * 2) ^ ((srow & 7) << 4));

    // issue h(0) first (Wf-frag setup hides its latency)
    f32x4 q0 = *(const f32x4*)(hg);
    f32x4 q1 = *(const f32x4*)(hg + 4);

    // Wf B-frags from packed bf16: 2 n-frags x 8 k = 32 VGPR, no packs
    bf16x8 wfr[2][8];
    float bfr[2];
#pragma unroll
    for (int n = 0; n < 2; ++n) {
        const short* wr = wpk + (size_t)(wc0 + n * 16 + l15) * DD + l4 * 8;
#pragma unroll
        for (int k = 0; k < 8; ++k) wfr[n][k] = *(const bf16x8*)(wr + k * 32);
        bfr[n] = bfv[wc0 + n * 16 + l15];
    }

    float hs[8], nmv[8];
#pragma unroll
    for (int i = 0; i < 8; ++i) { hs[i] = 0.f; nmv[i] = 0.f; }

    const float* cmp = cmem + (size_t)(b0 + l4 * 4) * DD + wc0 + l15;
    float cmA[8], cmB[8];
    f32x4 p0, p1;

    // ---- prologue: issue h(1), cm(0); then consume h(0): hs+, pack, write buf0
    {
        const float* h1 = hg + SLAB;
        p0 = *(const f32x4*)(h1);
        p1 = *(const f32x4*)(h1 + 4);
#pragma unroll
        for (int n = 0; n < 2; ++n)
#pragma unroll
            for (int j = 0; j < 4; ++j) cmA[n * 4 + j] = cmp[j * DD + n * 16];
#pragma unroll
        for (int i = 0; i < 4; ++i) { hs[i] += q0[i]; hs[4 + i] += q1[i]; }
        *(bf16x8*)(&hb[0][0] + wb) = pack8(q0, q1);
        // swap so iter 0 sees Q=h(1) in q, P free
        q0 = p0; q1 = p1;
        asm volatile("s_waitcnt lgkmcnt(0)" ::: "memory");
        __builtin_amdgcn_s_barrier();
        __builtin_amdgcn_sched_barrier(0);
    }

// iter c: buf[PAR]=h(c); Q=h(c+1) arriving; CMU=cm(c) arriving.
// loads: P<-h(c+2), CMF<-cm(c+1).  One lgkm drain + barrier per child.
#define CHILD(c, PAR, Q0, Q1, P0, P1, CMU, CMF)                               \
    {                                                                         \
        if ((c) + 2 < CC) {                                                   \
            const float* hn = hg + (size_t)((c) + 2) * SLAB;                  \
            P0 = *(const f32x4*)(hn);                                         \
            P1 = *(const f32x4*)(hn + 4);                                     \
        }                                                                     \
        if ((c) + 1 < CC) {                                                   \
            const float* cn = cmp + (size_t)((c) + 1) * SLAB;                 \
            _Pragma("unroll") for (int n = 0; n < 2; ++n)                     \
            _Pragma("unroll") for (int j = 0; j < 4; ++j)                     \
                CMF[n * 4 + j] = cn[j * DD + n * 16];                         \
        }                                                                     \
        f32x4 acc0 = {bfr[0], bfr[0], bfr[0], bfr[0]};                        \
        f32x4 acc1 = {bfr[1], bfr[1], bfr[1], bfr[1]};                        \
        const unsigned char* bc = &hb[PAR][0] + l15 * 512;                    \
        _Pragma("unroll") for (int kk = 0; kk < 8; ++kk) {                    \
            bf16x8 a = *(const bf16x8*)(bc + (((kk << 6) + (l4 << 4)) ^ sw15)); \
            acc0 = __builtin_amdgcn_mfma_f32_16x16x32_bf16(a, wfr[0][kk], acc0, 0, 0, 0); \
            acc1 = __builtin_amdgcn_mfma_f32_16x16x32_bf16(a, wfr[1][kk], acc1, 0, 0, 0); \
        }                                                                     \
        _Pragma("unroll") for (int j = 0; j < 4; ++j) {                       \
            nmv[j]     += sigm(acc0[j]) * CMU[j];                             \
            nmv[4 + j] += sigm(acc1[j]) * CMU[4 + j];                         \
        }                                                                     \
        if ((c) + 1 < CC) {                                                   \
            _Pragma("unroll") for (int i = 0; i < 4; ++i) {                   \
                hs[i] += Q0[i]; hs[4 + i] += Q1[i];                           \
            }                                                                 \
            *(bf16x8*)(&hb[(PAR) ^ 1][0] + wb) = pack8(Q0, Q1);               \
            asm volatile("s_waitcnt lgkmcnt(0)" ::: "memory");                \
            __builtin_amdgcn_s_barrier();                                     \
            __builtin_amdgcn_sched_barrier(0);                                \
        }                                                                     \
    }

    for (int cc = 0; cc < CC; cc += 2) {
        CHILD(cc,     0, q0, q1, p0, p1, cmA, cmB);
        CHILD(cc + 1, 1, p0, p1, q0, q1, cmB, cmA);
    }
#undef CHILD

    // ---- epilogue: hidden_sum -> LDS buf0 (own slot; all waves past barrier 14)
    {
        f32x4 e0 = {hs[0], hs[1], hs[2], hs[3]};
        f32x4 e1 = {hs[4], hs[5], hs[6], hs[7]};
        *(bf16x8*)(&hb[0][0] + wb) = pack8(e0, e1);
    }
    asm volatile("s_waitcnt lgkmcnt(0)" ::: "memory");
    __builtin_amdgcn_s_barrier();
    __builtin_amdgcn_sched_barrier(0);

    bf16x8 afr[8];
    {
        const unsigned char* bc = &hb[0][0] + l15 * 512;
#pragma unroll
        for (int kk = 0; kk < 8; ++kk)
            afr[kk] = *(const bf16x8*)(bc + (((kk << 6) + (l4 << 4)) ^ sw15));
    }

    // iou GEMM from packed Wiou (bf16, rows 256..1023 of wpk): no packs
    float gq[3][8];
#pragma unroll
    for (int q = 0; q < 3; ++q) {
#pragma unroll
        for (int n = 0; n < 2; ++n) {
            const short* wr = wpk + (size_t)(256 + q * 256 + wc0 + n * 16 + l15) * DD + l4 * 8;
            f32x4 acc = {0.f, 0.f, 0.f, 0.f};
#pragma unroll
            for (int kk = 0; kk < 8; ++kk)
                acc = __builtin_amdgcn_mfma_f32_16x16x32_bf16(afr[kk], *(const bf16x8*)(wr + kk * 32), acc, 0, 0, 0);
            float bq = biou[q * 256 + wc0 + n * 16 + l15];
#pragma unroll
            for (int j = 0; j < 4; ++j) gq[q][n * 4 + j] = acc[j] + bq;
        }
    }

    // ---- gates + stores
    float* o0 = out + (size_t)(b0 + l4 * 4) * DD + wc0 + l15;
    float* o1 = o0 + SLAB;
#pragma unroll
    for (int n = 0; n < 2; ++n)
#pragma unroll
        for (int j = 0; j < 4; ++j) {
            float ig = sigm(gq[0][n * 4 + j]);
            float og = sigm(gq[1][n * 4 + j]);
            float ug = tanh_(gq[2][n * 4 + j]);
            float mm = nmv[n * 4 + j] + ig * ug;
            float hh = og * tanh_(mm);
            o0[j * DD + n * 16] = mm;
            o1[j * DD + n * 16] = hh;
        }
}

extern "C" void kernel_launch(void* const* d_in, const int* in_sizes, int n_in,
                              void* d_out, int out_size, void* d_ws, size_t ws_size,
                              hipStream_t stream) {
    const float* cmem = (const float*)d_in[0];
    const float* chid = (const float*)d_in[1];
    const float* Wf   = (const float*)d_in[2];
    const float* bf   = (const float*)d_in[3];
    const float* Wiou = (const float*)d_in[4];
    const float* biou = (const float*)d_in[5];
    float* out = (float*)d_out;
    short* wpk = (short*)d_ws;    // 1024 x 256 bf16 = 512 KiB

    prep<<<1024, 64, 0, stream>>>(Wf, Wiou, wpk);
    treelstm<<<BB / BT, NT, 0, stream>>>(cmem, chid, wpk, bf, biou, out);
}